// Round 8
// baseline (501.382 us; speedup 1.0000x reference)
//
#include <hip/hip_runtime.h>
#include <hip/hip_fp16.h>

#define B_N 65536
#define K_N 256
#define D_N 128
#define N_ITER 50
#define NSHARD 16
#define NBLK 256                  // persist grid: 256 blocks x 1024 threads
#define GRPSZ 16                  // 16 groups of 16 blocks -> 16 leaf counters
#define NGRP 16
#define BUFSTRIDE (NSHARD * K_N)  // 4096 floats per colsum buffer (16 shards x 256)
#define EVPAD 20                  // ev_lds stride: 20 floats per 16-col chunk -> 2-way banks (free)

// --- flat barrier layout: per iteration, 16 leaf-counter cachelines ---
// (BAR_ITER_U kept at 65 lines so the init zeroing covers generously)
#define BAR_LINES 65
#define BAR_ITER_U (BAR_LINES * 16)  // 1040 uints per iteration

constexpr float MU_EPS = 1.0f / 65536.0f + 1e-8f;  // exp(log_mu)
constexpr float NU_EPS = 1.0f / 256.0f + 1e-8f;    // exp(log_nu)
constexpr float KSCALE = 8192.0f;                  // keeps fp16 kappa in normal range
constexpr float INV_KSCALE = 1.0f / 8192.0f;
constexpr float NUKS = NU_EPS * KSCALE;
constexpr float MUKS = MU_EPS * KSCALE;

typedef __attribute__((ext_vector_type(8))) short bf16x8;
typedef __attribute__((ext_vector_type(4))) float f32x4;

union frag_u { uint4 u; bf16x8 v; };

__device__ __forceinline__ float wave_sum(float v) {
#pragma unroll
    for (int m = 1; m < 64; m <<= 1) v += __shfl_xor(v, m, 64);
    return v;
}

// round-to-nearest-even fp32 -> bf16 bit pattern (as short)
__device__ __forceinline__ short f32_to_bf16(float x) {
    unsigned u = __float_as_uint(x);
    return (short)((u + 0x7FFFu + ((u >> 16) & 1u)) >> 16);
}
__device__ __forceinline__ float bf16_hi_f32(float x) {  // value of bf16(x)
    unsigned u = __float_as_uint(x);
    unsigned r = ((u + 0x7FFFu + ((u >> 16) & 1u)) >> 16) << 16;
    return __uint_as_float(r);
}

// ---------------------------------------------------------------------------
// Blocks 0..255: L2-normalize prototype rows; emit split-bf16 hi/lo planes in
// FRAGMENT-SWIZZLED order so gemm's per-(w,ct,ks) fragment load is one
// contiguous coalesced 1KB read.
// dest(col,k): w=col>>6, ct=(col>>4)&3, m=col&15, ks=k>>5, q=(k>>3)&3, j=k&7
//   off = (((w*4+ct)*4+ks)*64 + q*16+m)*8 + j
// Blocks 256..263: zero the 50x65-line barrier region (uint4, 8-way split).
// Block 256 additionally: init colsum buffers (3-buffer rotation; buf2/shard0
// = NUKS so iteration 0 sees exp(v)=1) + zero d_out (harness poisons 0xAA).
// ---------------------------------------------------------------------------
__global__ __launch_bounds__(64) void proto_norm_init(
        const float* __restrict__ proto, short* __restrict__ bh_s,
        short* __restrict__ bl_s, float* __restrict__ csbuf,
        unsigned* __restrict__ bar, float* __restrict__ out) {
    const int blk = blockIdx.x;
    const int lane = threadIdx.x;
    if (blk < 256) {
        float2 p = *(const float2*)&proto[blk * 128 + lane * 2];
        float ss = wave_sum(p.x * p.x + p.y * p.y);
        float inv = 1.0f / fmaxf(sqrtf(ss), 1e-12f);
        float v0 = p.x * inv, v1 = p.y * inv;
        short2 h, l;
        h.x = f32_to_bf16(v0); h.y = f32_to_bf16(v1);
        l.x = f32_to_bf16(v0 - bf16_hi_f32(v0));
        l.y = f32_to_bf16(v1 - bf16_hi_f32(v1));
        const int k0 = lane * 2;
        const int ks = k0 >> 5, qq = (k0 >> 3) & 3, j = k0 & 7;
        const int mm = blk & 15, ct = (blk >> 4) & 3, ww = blk >> 6;
        const size_t off = (size_t)((((ww * 4 + ct) * 4 + ks) * 64 + qq * 16 + mm)) * 8 + j;
        *(short2*)&bh_s[off] = h;
        *(short2*)&bl_s[off] = l;
    } else {
        const int z = blk - 256;  // 0..7
        uint4* b4 = (uint4*)bar;
        const uint4 zero4 = {0u, 0u, 0u, 0u};
        const int total4 = N_ITER * BAR_ITER_U / 4;  // 13000
        for (int i = z * 64 + lane; i < total4; i += 512) b4[i] = zero4;
        if (z == 0) {
            for (int i = lane; i < 3 * BUFSTRIDE; i += 64)
                csbuf[i] = (i >= 2 * BUFSTRIDE && i < 2 * BUFSTRIDE + K_N) ? NUKS : 0.0f;
            if (lane == 0) out[0] = 0.0f;
        }
    }
}

// ---------------------------------------------------------------------------
// Split-bf16 MFMA GEMM with FUSED row-norm: C[i,k] = 1 - (x_i.yn_k)/||x_i||.
// A-side hi/lo split via v_cvt_pk_bf16_f32; al = v - value(ah) keeps ~2^-16
// accuracy regardless of rounding mode. B hi/lo register-resident from the
// swizzled planes (coalesced 1KB loads). Unchanged from round 7 (passed).
// ---------------------------------------------------------------------------
__global__ __launch_bounds__(256, 2) void gemm_mfma(
        const float* __restrict__ x, const short* __restrict__ bh_s,
        const short* __restrict__ bl_s, __half* __restrict__ kappa) {
    const int tid = threadIdx.x;
    const int w = tid >> 6, lane = tid & 63;
    const int q = lane >> 4, m = lane & 15;
    const int row0 = blockIdx.x * 64;
    const int colbase = w * 64;
    bf16x8 bh[4][4], bl[4][4];
#pragma unroll
    for (int ct = 0; ct < 4; ct++) {
#pragma unroll
        for (int ks = 0; ks < 4; ks++) {
            const size_t off = (size_t)((((w * 4 + ct) * 4 + ks) * 64 + lane)) * 8;
            bh[ct][ks] = *(const bf16x8*)&bh_s[off];
            bl[ct][ks] = *(const bf16x8*)&bl_s[off];
        }
    }
#pragma unroll
    for (int rt = 0; rt < 4; rt++) {
        const int arow = row0 + rt * 16 + m;
        float av[4][8];
        float ss = 0.0f;
#pragma unroll
        for (int ks = 0; ks < 4; ks++) {
            const float* ap = &x[(size_t)arow * 128 + ks * 32 + q * 8];
            float4 a0 = *(const float4*)ap;
            float4 a1 = *(const float4*)(ap + 4);
            av[ks][0] = a0.x; av[ks][1] = a0.y; av[ks][2] = a0.z; av[ks][3] = a0.w;
            av[ks][4] = a1.x; av[ks][5] = a1.y; av[ks][6] = a1.z; av[ks][7] = a1.w;
#pragma unroll
            for (int j = 0; j < 8; j++) ss = fmaf(av[ks][j], av[ks][j], ss);
        }
        // row ||x||^2: lanes {m, m+16, m+32, m+48} hold the row's 4 k-chunks
        ss += __shfl_xor(ss, 16, 64);
        ss += __shfl_xor(ss, 32, 64);
        const float rnv = 1.0f / fmaxf(sqrtf(ss), 1e-12f);
        frag_u ah[4], al[4];
#pragma unroll
        for (int ks = 0; ks < 4; ks++) {
            unsigned uh[4], ul[4];
#pragma unroll
            for (int p = 0; p < 4; p++) {
                float a0 = av[ks][2 * p] * rnv;
                float a1 = av[ks][2 * p + 1] * rnv;
                unsigned u;
                asm("v_cvt_pk_bf16_f32 %0, %1, %2" : "=v"(u) : "v"(a0), "v"(a1));
                float h0 = __uint_as_float(u << 16);
                float h1 = __uint_as_float(u & 0xffff0000u);
                float l0 = a0 - h0, l1 = a1 - h1;
                unsigned u2;
                asm("v_cvt_pk_bf16_f32 %0, %1, %2" : "=v"(u2) : "v"(l0), "v"(l1));
                uh[p] = u; ul[p] = u2;
            }
            ah[ks].u = make_uint4(uh[0], uh[1], uh[2], uh[3]);
            al[ks].u = make_uint4(ul[0], ul[1], ul[2], ul[3]);
        }
        f32x4 acc[4];
#pragma unroll
        for (int ct = 0; ct < 4; ct++) acc[ct] = (f32x4){0.f, 0.f, 0.f, 0.f};
#pragma unroll
        for (int ks = 0; ks < 4; ks++) {
#pragma unroll
            for (int ct = 0; ct < 4; ct++) {
                acc[ct] = __builtin_amdgcn_mfma_f32_16x16x32_bf16(ah[ks].v, bh[ct][ks], acc[ct], 0, 0, 0);
                acc[ct] = __builtin_amdgcn_mfma_f32_16x16x32_bf16(al[ks].v, bh[ct][ks], acc[ct], 0, 0, 0);
                acc[ct] = __builtin_amdgcn_mfma_f32_16x16x32_bf16(ah[ks].v, bl[ct][ks], acc[ct], 0, 0, 0);
            }
        }
        // epilogue: C/D map col=m, row=q*4+r; 16 lanes -> 32B contiguous runs
#pragma unroll
        for (int ct = 0; ct < 4; ct++) {
            const int ocol = colbase + ct * 16 + m;
#pragma unroll
            for (int r = 0; r < 4; r++) {
                const int orow = row0 + rt * 16 + q * 4 + r;
                float Cv = 1.0f - acc[ct][r];
                kappa[(size_t)orow * 256 + ocol] =
                    __float2half(KSCALE * (__expf(-10.0f * Cv) + 1e-8f));
            }
        }
    }
}

// ---------------------------------------------------------------------------
// PERSISTENT kernel: all 50 Sinkhorn iterations + finalize.
// Round-8 barrier: FLAT one-hop. Round-7's two-level tree cost 3 sequential
// IC round-trips (leaf RMW -> root RMW -> flag store) before pollers could
// see release — ~3.5us of the 6.1us/iter. Now: 256 blocks arrive on 16 leaf
// counters (16 RMWs each, overlapped); wave 0 of EVERY block polls all 16
// counters in parallel (lane i loads leaf[i&15], one memory instruction,
// __all(v>=16) ends the loop). Chain = last RMW -> one poll round. All ops
// RELAXED agent-scope (acquire-spin = invalidate storm, round-2; plain load
// polling is benign, proven round-3/4). Payload ops all IC-point atomics;
// __syncthreads drains vmcnt before arrival. Co-residency: 256 blocks at 1
// block/CU (VGPR 64, LDS 19 KB); sticky ~42ms timeout bails, never hangs.
// ---------------------------------------------------------------------------
__global__ __launch_bounds__(1024, 4) void sinkhorn_persist(
        const __half* __restrict__ kappa, float* __restrict__ csbuf,
        const float* __restrict__ coord, unsigned* __restrict__ bar,
        float* __restrict__ out) {
    __shared__ __align__(16) float ev_lds[16 * EVPAD];  // [chunk c][j] stride-20, 2-way banks
    __shared__ float cs_lds[16 * 273];  // [wave][chunk*17 + j] stride-17, conflict-free
    __shared__ float wpart[16];
    const int blk = blockIdx.x, tid = threadIdx.x;
    const int w = tid >> 6, lane = tid & 63;
    const int g = lane >> 4, c = lane & 15;
    const int row_base = blk * 256 + w * 16 + g;  // + rg*4
    const uint4* kb = (const uint4*)kappa;        // 8 halves per uint4; row = 32 uint4
    uint4 kv[4][2];                               // this thread's kappa slice, loop-invariant
#pragma unroll
    for (int rg = 0; rg < 4; rg++) {
        const size_t base = (size_t)(row_base + rg * 4) * 32 + c * 2;
        kv[rg][0] = kb[base];
        kv[rg][1] = kb[base + 1];
    }
    float ai_reg[4] = {0.f, 0.f, 0.f, 0.f};      // exp(u) of this thread's 4 rows
    bool dead = false;                           // sticky barrier-timeout flag (wave 0)
    for (int t = 0; t < N_ITER; t++) {
        const int p_read = (t + 2) % 3, p_acc = t % 3, p_zero = (t + 1) % 3;
        if (tid < 256) {  // ev_k = NUKS / colsum_k  (thread tid owns column tid)
            const float* cb = csbuf + p_read * BUFSTRIDE;
            float cs = 0.0f;
#pragma unroll
            for (int s = 0; s < NSHARD; s++)
                cs += __hip_atomic_load(&cb[s * 256 + tid], __ATOMIC_RELAXED,
                                        __HIP_MEMORY_SCOPE_AGENT);
            ev_lds[(tid >> 4) * EVPAD + (tid & 15)] = NUKS * __builtin_amdgcn_rcpf(cs);
        }
        if (blk < NSHARD && tid < 256)
            __hip_atomic_store(&csbuf[p_zero * BUFSTRIDE + blk * 256 + tid], 0.0f,
                               __ATOMIC_RELAXED, __HIP_MEMORY_SCOPE_AGENT);
        __syncthreads();
        float e[16];
        {
            const float* eb = &ev_lds[c * EVPAD];
            float4 e0 = *(const float4*)(eb + 0);
            float4 e1 = *(const float4*)(eb + 4);
            float4 e2 = *(const float4*)(eb + 8);
            float4 e3 = *(const float4*)(eb + 12);
            e[0] = e0.x; e[1] = e0.y; e[2] = e0.z; e[3] = e0.w;
            e[4] = e1.x; e[5] = e1.y; e[6] = e1.z; e[7] = e1.w;
            e[8] = e2.x; e[9] = e2.y; e[10] = e2.z; e[11] = e2.w;
            e[12] = e3.x; e[13] = e3.y; e[14] = e3.z; e[15] = e3.w;
        }
        float acc[16];
#pragma unroll
        for (int j = 0; j < 16; j++) acc[j] = 0.0f;
#pragma unroll
        for (int rg = 0; rg < 4; rg++) {
            float kf[16];
            const __half2* h0 = (const __half2*)&kv[rg][0];
            const __half2* h1 = (const __half2*)&kv[rg][1];
#pragma unroll
            for (int qq = 0; qq < 4; qq++) {
                float2 f = __half22float2(h0[qq]);
                kf[2 * qq] = f.x; kf[2 * qq + 1] = f.y;
                float2 f2 = __half22float2(h1[qq]);
                kf[8 + 2 * qq] = f2.x; kf[8 + 2 * qq + 1] = f2.y;
            }
            float part = 0.0f;
#pragma unroll
            for (int j = 0; j < 16; j++) part = fmaf(kf[j], e[j], part);
            part += __shfl_xor(part, 8, 64);   // 16-lane tree: 4 rows in parallel
            part += __shfl_xor(part, 4, 64);
            part += __shfl_xor(part, 2, 64);
            part += __shfl_xor(part, 1, 64);
            float ai = MUKS * __builtin_amdgcn_rcpf(part);  // = exp(u_row)
            ai_reg[rg] = ai;
#pragma unroll
            for (int j = 0; j < 16; j++) acc[j] = fmaf(kf[j], ai, acc[j]);
        }
#pragma unroll
        for (int j = 0; j < 16; j++) {
            acc[j] += __shfl_xor(acc[j], 16, 64);
            acc[j] += __shfl_xor(acc[j], 32, 64);
        }
        if (g == 0) {
#pragma unroll
            for (int j = 0; j < 16; j++) cs_lds[w * 273 + c * 17 + j] = acc[j];
        }
        __syncthreads();
        if (tid < 256) {
            float v = 0.0f;
#pragma unroll
            for (int p = 0; p < 16; p++) v += cs_lds[p * 273 + (tid >> 4) * 17 + (tid & 15)];
            atomicAdd(&csbuf[p_acc * BUFSTRIDE + (blk & (NSHARD - 1)) * 256 + tid], v);
        }
        // ---- flat one-hop barrier: arrive on 16 leaf counters, all-lane poll ----
        __syncthreads();   // drains vmcnt(0): payload visible at coherent point
        if (tid == 0)
            __hip_atomic_fetch_add(&bar[t * BAR_ITER_U + (blk >> 4) * 16], 1u,
                                   __ATOMIC_RELAXED, __HIP_MEMORY_SCOPE_AGENT);
        if (w == 0 && !dead) {
            unsigned* cnt = &bar[t * BAR_ITER_U + (lane & 15) * 16];
            long long t0 = __builtin_amdgcn_s_memrealtime();
            while (true) {
                unsigned v = __hip_atomic_load(cnt, __ATOMIC_RELAXED,
                                               __HIP_MEMORY_SCOPE_AGENT);
                if (__all(v >= (unsigned)GRPSZ)) break;
                __builtin_amdgcn_s_sleep(2);
                if (__builtin_amdgcn_s_memrealtime() - t0 > (1LL << 22)) {
                    dead = true;  // ~42 ms: co-residency violated; bail, no hang
                    break;
                }
            }
        }
        __syncthreads();
    }
    // ---- epilogue == finalize, kappa + ai already in registers ----
    if (tid < 256) {
        const float* cb = csbuf + ((N_ITER - 1) % 3) * BUFSTRIDE;  // p_acc of t=49
        float cs = 0.0f;
#pragma unroll
        for (int s = 0; s < NSHARD; s++)
            cs += __hip_atomic_load(&cb[s * 256 + tid], __ATOMIC_RELAXED,
                                    __HIP_MEMORY_SCOPE_AGENT);
        ev_lds[(tid >> 4) * EVPAD + (tid & 15)] = NUKS * __builtin_amdgcn_rcpf(cs);
    }
    __syncthreads();
    float ef[16];
    {
        const float* eb = &ev_lds[c * EVPAD];
        float4 e0 = *(const float4*)(eb + 0);
        float4 e1 = *(const float4*)(eb + 4);
        float4 e2 = *(const float4*)(eb + 8);
        float4 e3 = *(const float4*)(eb + 12);
        ef[0] = e0.x; ef[1] = e0.y; ef[2] = e0.z; ef[3] = e0.w;
        ef[4] = e1.x; ef[5] = e1.y; ef[6] = e1.z; ef[7] = e1.w;
        ef[8] = e2.x; ef[9] = e2.y; ef[10] = e2.z; ef[11] = e2.w;
        ef[12] = e3.x; ef[13] = e3.y; ef[14] = e3.z; ef[15] = e3.w;
    }
    float accv = 0.0f;
#pragma unroll
    for (int rg = 0; rg < 4; rg++) {
        const int row = row_base + rg * 4;
        float kf[16];
        const __half2* h0 = (const __half2*)&kv[rg][0];
        const __half2* h1 = (const __half2*)&kv[rg][1];
#pragma unroll
        for (int qq = 0; qq < 4; qq++) {
            float2 f = __half22float2(h0[qq]);
            kf[2 * qq] = f.x; kf[2 * qq + 1] = f.y;
            float2 f2 = __half22float2(h1[qq]);
            kf[8 + 2 * qq] = f2.x; kf[8 + 2 * qq + 1] = f2.y;
        }
        const float* cp = &coord[(size_t)row * 256 + c * 16];
        float4 c0 = *(const float4*)(cp + 0);
        float4 c1 = *(const float4*)(cp + 4);
        float4 c2 = *(const float4*)(cp + 8);
        float4 c3 = *(const float4*)(cp + 12);
        float a[16] = {fabsf(c0.x), fabsf(c0.y), fabsf(c0.z), fabsf(c0.w),
                       fabsf(c1.x), fabsf(c1.y), fabsf(c1.z), fabsf(c1.w),
                       fabsf(c2.x), fabsf(c2.y), fabsf(c2.z), fabsf(c2.w),
                       fabsf(c3.x), fabsf(c3.y), fabsf(c3.z), fabsf(c3.w)};
        float mx = a[0];
#pragma unroll
        for (int j = 1; j < 16; j++) mx = fmaxf(mx, a[j]);
        mx = fmaxf(mx, __shfl_xor(mx, 8, 64));   // row lives in one 16-lane c-group
        mx = fmaxf(mx, __shfl_xor(mx, 4, 64));
        mx = fmaxf(mx, __shfl_xor(mx, 2, 64));
        mx = fmaxf(mx, __shfl_xor(mx, 1, 64));
        float ex[16];
        float zs = 0.0f;
#pragma unroll
        for (int j = 0; j < 16; j++) { ex[j] = __expf(a[j] - mx); zs += ex[j]; }
        zs += __shfl_xor(zs, 8, 64);
        zs += __shfl_xor(zs, 4, 64);
        zs += __shfl_xor(zs, 2, 64);
        zs += __shfl_xor(zs, 1, 64);
        float s = 0.0f;
#pragma unroll
        for (int j = 0; j < 16; j++) {
            float Cj = -0.1f * __logf(kf[j] * INV_KSCALE - 1e-8f);
            s += kf[j] * ef[j] * Cj * ex[j];
        }
        accv = fmaf(s, ai_reg[rg] * INV_KSCALE * __builtin_amdgcn_rcpf(zs), accv);
    }
    accv = wave_sum(accv);
    if (lane == 0) wpart[w] = accv;
    __syncthreads();
    if (tid == 0) {
        float tot = 0.0f;
#pragma unroll
        for (int i = 0; i < 16; i++) tot += wpart[i];
        atomicAdd(out, tot);
    }
}

extern "C" void kernel_launch(void* const* d_in, const int* in_sizes, int n_in,
                              void* d_out, int out_size, void* d_ws, size_t ws_size,
                              hipStream_t stream) {
    const float* x = (const float*)d_in[0];
    const float* proto = (const float*)d_in[1];
    const float* coord = (const float*)d_in[2];
    float* out = (float*)d_out;
    char* ws = (char*)d_ws;
    // workspace layout (~34.2 MB)
    __half* kappa = (__half*)(ws);                          // 32 MB
    short* bh_s = (short*)(ws + 33554432);                  // 64 KB (swizzled hi plane)
    short* bl_s = bh_s + 32768;                             // 64 KB (swizzled lo plane)
    unsigned* bar = (unsigned*)(ws + 33554432 + 131072 + 262144);       // 208 KB barrier region
    float* csbuf = (float*)(ws + 33554432 + 131072 + 262144 + 262144);  // 48 KB

    hipLaunchKernelGGL(proto_norm_init, dim3(264), dim3(64), 0, stream,
                       proto, bh_s, bl_s, csbuf, bar, out);
    hipLaunchKernelGGL(gemm_mfma, dim3(1024), dim3(256), 0, stream, x, bh_s, bl_s, kappa);
    hipLaunchKernelGGL(sinkhorn_persist, dim3(NBLK), dim3(1024), 0, stream,
                       kappa, csbuf, coord, bar, out);
}

// Round 9
// 406.396 us; speedup vs baseline: 1.2337x; 1.2337x over previous
//
#include <hip/hip_runtime.h>
#include <hip/hip_fp16.h>

#define B_N 65536
#define K_N 256
#define D_N 128
#define N_ITER 50
#define NSHARD 16
#define NBLK 256                  // persist grid: 256 blocks x 1024 threads
#define GRPSZ 16                  // 16 groups of 16 blocks -> 16 leaf counters
#define BUFSTRIDE (NSHARD * K_N)  // 4096 floats per colsum buffer (16 shards x 256)
#define EVPAD 20                  // ev_lds stride: 20 floats per 16-col chunk -> 2-way banks

// --- barrier layout per iteration (65 lines of 16 uints, all zeroed) ---
//   lines 0..15 : leaf arrival counters (RMW targets — NEVER polled)
//   lines 33..48: per-group done flags (store-only — the ONLY polled lines)
#define BAR_LINES 65
#define BAR_ITER_U (BAR_LINES * 16)  // 1040 uints per iteration

constexpr float MU_EPS = 1.0f / 65536.0f + 1e-8f;  // exp(log_mu)
constexpr float NU_EPS = 1.0f / 256.0f + 1e-8f;    // exp(log_nu)
constexpr float KSCALE = 8192.0f;                  // kept for arithmetic identity w/ verified path
constexpr float INV_KSCALE = 1.0f / 8192.0f;
constexpr float NUKS = NU_EPS * KSCALE;
constexpr float MUKS = MU_EPS * KSCALE;

typedef __attribute__((ext_vector_type(8))) short bf16x8;
typedef __attribute__((ext_vector_type(4))) float f32x4;

union frag_u { uint4 u; bf16x8 v; };

__device__ __forceinline__ float wave_sum(float v) {
#pragma unroll
    for (int m = 1; m < 64; m <<= 1) v += __shfl_xor(v, m, 64);
    return v;
}

// round-to-nearest-even fp32 -> bf16 bit pattern (as short)
__device__ __forceinline__ short f32_to_bf16(float x) {
    unsigned u = __float_as_uint(x);
    return (short)((u + 0x7FFFu + ((u >> 16) & 1u)) >> 16);
}
__device__ __forceinline__ float bf16_hi_f32(float x) {  // value of bf16(x)
    unsigned u = __float_as_uint(x);
    unsigned r = ((u + 0x7FFFu + ((u >> 16) & 1u)) >> 16) << 16;
    return __uint_as_float(r);
}

// ---------------------------------------------------------------------------
// Blocks 0..255: L2-normalize prototype rows; emit split-bf16 hi/lo planes in
// fragment-swizzled order: off(col,k) = ((CT*4+ks)*64 + q*16+m)*8 + j where
// CT=col>>4, m=col&15, ks=k>>5, q=(k>>3)&3, j=k&7 — so the fused gemm's
// per-(CT,ks) fragment load is one contiguous coalesced 1KB read.
// Blocks 256..263: zero the 50x65-line barrier region.
// Block 256 additionally: init colsum buffers (3-buffer rotation; buf2/shard0
// = NUKS so iteration 0 sees exp(v)=1) + zero d_out (harness poisons 0xAA).
// ---------------------------------------------------------------------------
__global__ __launch_bounds__(64) void proto_norm_init(
        const float* __restrict__ proto, short* __restrict__ bh_s,
        short* __restrict__ bl_s, float* __restrict__ csbuf,
        unsigned* __restrict__ bar, float* __restrict__ out) {
    const int blk = blockIdx.x;
    const int lane = threadIdx.x;
    if (blk < 256) {
        float2 p = *(const float2*)&proto[blk * 128 + lane * 2];
        float ss = wave_sum(p.x * p.x + p.y * p.y);
        float inv = 1.0f / fmaxf(sqrtf(ss), 1e-12f);
        float v0 = p.x * inv, v1 = p.y * inv;
        short2 h, l;
        h.x = f32_to_bf16(v0); h.y = f32_to_bf16(v1);
        l.x = f32_to_bf16(v0 - bf16_hi_f32(v0));
        l.y = f32_to_bf16(v1 - bf16_hi_f32(v1));
        const int k0 = lane * 2;
        const int ks = k0 >> 5, qq = (k0 >> 3) & 3, j = k0 & 7;
        const int mm = blk & 15, CT = blk >> 4;
        const size_t off = (size_t)(((CT * 4 + ks) * 64 + qq * 16 + mm)) * 8 + j;
        *(short2*)&bh_s[off] = h;
        *(short2*)&bl_s[off] = l;
    } else {
        const int z = blk - 256;  // 0..7
        uint4* b4 = (uint4*)bar;
        const uint4 zero4 = {0u, 0u, 0u, 0u};
        const int total4 = N_ITER * BAR_ITER_U / 4;  // 13000
        for (int i = z * 64 + lane; i < total4; i += 512) b4[i] = zero4;
        if (z == 0) {
            for (int i = lane; i < 3 * BUFSTRIDE; i += 64)
                csbuf[i] = (i >= 2 * BUFSTRIDE && i < 2 * BUFSTRIDE + K_N) ? NUKS : 0.0f;
            if (lane == 0) out[0] = 0.0f;
        }
    }
}

// ---------------------------------------------------------------------------
// FULLY-FUSED PERSISTENT kernel: in-register GEMM + 50 Sinkhorn iters + final.
// 256 blocks x 1024 threads, 1 block/CU. Block owns rows blk*256..+255; wave
// w computes its 16-row x 256-col kappa tile via split-bf16 MFMA (B streamed
// from the L2-hot 128KB swizzled planes) and keeps it in registers as f32
// kvf[4][16] — kappa NEVER touches memory (kills the 32MB write + 32MB read
// + fp16 cvts + a kernel launch). Thread (w,q,m) owns rows w*16+q*4+{0..3},
// cols {j*16+m : j=0..15} (the native MFMA C/D layout).
// Barrier (round-9): 2-hop, store-only poll targets. Arrivals RMW 16 leaf
// counters (never polled — round-8 lesson: polling RMW lines stalls the
// atomic unit, +75us); group-last (prev==15) STOREs a per-group done flag;
// wave 0 of every block polls the 16 done lines with one coalesced 64-lane
// load + __all. All ops RELAXED agent-scope (acquire-spin = invalidate storm,
// round-2). Payload ops are IC-point atomics; __syncthreads drains vmcnt
// before arrival. Sticky ~42ms timeout bails instead of hanging.
// ---------------------------------------------------------------------------
__global__ __launch_bounds__(1024, 4) void sinkhorn_persist(
        const float* __restrict__ x, const short* __restrict__ bh_s,
        const short* __restrict__ bl_s, float* __restrict__ csbuf,
        const float* __restrict__ coord, unsigned* __restrict__ bar,
        float* __restrict__ out) {
    __shared__ __align__(16) float ev_lds[16 * EVPAD];  // [chunk][idx] stride-20
    __shared__ float cs_lds[16 * 273];  // [wave][chunk*17 + idx] stride-17
    __shared__ float wpart[16];
    const int blk = blockIdx.x, tid = threadIdx.x;
    const int w = tid >> 6, lane = tid & 63;
    const int q = lane >> 4, m = lane & 15;

    // ---- phase 0: fused split-bf16 MFMA GEMM + row-norm, kappa -> registers ----
    const int arow = blk * 256 + w * 16 + m;   // A-tile row for this lane
    float av[4][8];
    float ss = 0.0f;
#pragma unroll
    for (int ks = 0; ks < 4; ks++) {
        const float* ap = &x[(size_t)arow * 128 + ks * 32 + q * 8];
        float4 a0 = *(const float4*)ap;
        float4 a1 = *(const float4*)(ap + 4);
        av[ks][0] = a0.x; av[ks][1] = a0.y; av[ks][2] = a0.z; av[ks][3] = a0.w;
        av[ks][4] = a1.x; av[ks][5] = a1.y; av[ks][6] = a1.z; av[ks][7] = a1.w;
#pragma unroll
        for (int j = 0; j < 8; j++) ss = fmaf(av[ks][j], av[ks][j], ss);
    }
    ss += __shfl_xor(ss, 16, 64);   // row m's 4 k-chunks live at lanes {m,m+16,m+32,m+48}
    ss += __shfl_xor(ss, 32, 64);
    const float rnv = 1.0f / fmaxf(sqrtf(ss), 1e-12f);
    frag_u ah[4], al[4];
#pragma unroll
    for (int ks = 0; ks < 4; ks++) {
        unsigned uh[4], ul[4];
#pragma unroll
        for (int p = 0; p < 4; p++) {
            float a0 = av[ks][2 * p] * rnv;
            float a1 = av[ks][2 * p + 1] * rnv;
            unsigned u;
            asm("v_cvt_pk_bf16_f32 %0, %1, %2" : "=v"(u) : "v"(a0), "v"(a1));
            float h0 = __uint_as_float(u << 16);
            float h1 = __uint_as_float(u & 0xffff0000u);
            float l0 = a0 - h0, l1 = a1 - h1;
            unsigned u2;
            asm("v_cvt_pk_bf16_f32 %0, %1, %2" : "=v"(u2) : "v"(l0), "v"(l1));
            uh[p] = u; ul[p] = u2;
        }
        ah[ks].u = make_uint4(uh[0], uh[1], uh[2], uh[3]);
        al[ks].u = make_uint4(ul[0], ul[1], ul[2], ul[3]);
    }
    float kvf[4][16];   // kvf[r][CT]: kappa(row w*16+q*4+r, col CT*16+m), f32
    {
        f32x4 acc[16];
#pragma unroll
        for (int CT = 0; CT < 16; CT++) acc[CT] = (f32x4){0.f, 0.f, 0.f, 0.f};
#pragma unroll
        for (int ks = 0; ks < 4; ks++) {
#pragma unroll
            for (int CT = 0; CT < 16; CT++) {
                const size_t off = (size_t)(((CT * 4 + ks) * 64 + lane)) * 8;
                bf16x8 bh = *(const bf16x8*)&bh_s[off];
                bf16x8 bl = *(const bf16x8*)&bl_s[off];
                acc[CT] = __builtin_amdgcn_mfma_f32_16x16x32_bf16(ah[ks].v, bh, acc[CT], 0, 0, 0);
                acc[CT] = __builtin_amdgcn_mfma_f32_16x16x32_bf16(al[ks].v, bh, acc[CT], 0, 0, 0);
                acc[CT] = __builtin_amdgcn_mfma_f32_16x16x32_bf16(ah[ks].v, bl, acc[CT], 0, 0, 0);
            }
        }
#pragma unroll
        for (int CT = 0; CT < 16; CT++) {
#pragma unroll
            for (int r = 0; r < 4; r++) {
                float Cv = 1.0f - acc[CT][r];
                kvf[r][CT] = KSCALE * (__expf(-10.0f * Cv) + 1e-8f);
            }
        }
    }

    // ---- phase 1: 50 Sinkhorn iterations ----
    float ai_reg[4] = {0.f, 0.f, 0.f, 0.f};
    bool dead = false;
    for (int t = 0; t < N_ITER; t++) {
        const int p_read = (t + 2) % 3, p_acc = t % 3, p_zero = (t + 1) % 3;
        if (tid < 256) {  // ev_k = NUKS / colsum_k (thread tid owns column tid)
            const float* cb = csbuf + p_read * BUFSTRIDE;
            float cs = 0.0f;
#pragma unroll
            for (int s = 0; s < NSHARD; s++)
                cs += __hip_atomic_load(&cb[s * 256 + tid], __ATOMIC_RELAXED,
                                        __HIP_MEMORY_SCOPE_AGENT);
            ev_lds[(tid >> 4) * EVPAD + (tid & 15)] = NUKS * __builtin_amdgcn_rcpf(cs);
        }
        if (blk < NSHARD && tid < 256)
            __hip_atomic_store(&csbuf[p_zero * BUFSTRIDE + blk * 256 + tid], 0.0f,
                               __ATOMIC_RELAXED, __HIP_MEMORY_SCOPE_AGENT);
        __syncthreads();
        float e[16];   // e[j] = ev[col j*16+m]
#pragma unroll
        for (int j = 0; j < 16; j++) e[j] = ev_lds[j * EVPAD + m];
        float acc[16];
#pragma unroll
        for (int j = 0; j < 16; j++) acc[j] = 0.0f;
#pragma unroll
        for (int rg = 0; rg < 4; rg++) {
            float part = 0.0f;
#pragma unroll
            for (int j = 0; j < 16; j++) part = fmaf(kvf[rg][j], e[j], part);
            part += __shfl_xor(part, 8, 64);   // reduce over the 16 m-lanes
            part += __shfl_xor(part, 4, 64);
            part += __shfl_xor(part, 2, 64);
            part += __shfl_xor(part, 1, 64);
            float ai = MUKS * __builtin_amdgcn_rcpf(part);  // = exp(u_row)
            ai_reg[rg] = ai;
#pragma unroll
            for (int j = 0; j < 16; j++) acc[j] = fmaf(kvf[rg][j], ai, acc[j]);
        }
#pragma unroll
        for (int j = 0; j < 16; j++) {   // reduce over q (the wave's 16 rows)
            acc[j] += __shfl_xor(acc[j], 16, 64);
            acc[j] += __shfl_xor(acc[j], 32, 64);
        }
        if (q == 0) {  // lanes m=0..15 hold colsum for cols j*16+m
#pragma unroll
            for (int j = 0; j < 16; j++) cs_lds[w * 273 + j * 17 + m] = acc[j];
        }
        __syncthreads();
        if (tid < 256) {
            float v = 0.0f;
#pragma unroll
            for (int p = 0; p < 16; p++) v += cs_lds[p * 273 + (tid >> 4) * 17 + (tid & 15)];
            atomicAdd(&csbuf[p_acc * BUFSTRIDE + (blk & (NSHARD - 1)) * 256 + tid], v);
        }
        // ---- 2-hop barrier: RMW leafs (unpolled) -> store done flags (polled) ----
        __syncthreads();   // drains vmcnt(0): payload visible at coherent point
        if (tid == 0) {
            unsigned prev = __hip_atomic_fetch_add(
                &bar[t * BAR_ITER_U + (blk >> 4) * 16], 1u,
                __ATOMIC_RELAXED, __HIP_MEMORY_SCOPE_AGENT);
            if (prev == (unsigned)(GRPSZ - 1))
                __hip_atomic_store(&bar[t * BAR_ITER_U + (33 + (blk >> 4)) * 16], 1u,
                                   __ATOMIC_RELAXED, __HIP_MEMORY_SCOPE_AGENT);
        }
        if (w == 0 && !dead) {
            unsigned* dp = &bar[t * BAR_ITER_U + (33 + (lane & 15)) * 16];
            long long t0 = __builtin_amdgcn_s_memrealtime();
            while (true) {
                unsigned v = __hip_atomic_load(dp, __ATOMIC_RELAXED,
                                               __HIP_MEMORY_SCOPE_AGENT);
                if (__all(v != 0u)) break;
                __builtin_amdgcn_s_sleep(4);
                if (__builtin_amdgcn_s_memrealtime() - t0 > (1LL << 22)) {
                    dead = true;  // ~42 ms: co-residency violated; bail, no hang
                    break;
                }
            }
        }
        __syncthreads();
    }

    // ---- phase 2: finalize (kappa + ai in registers) ----
    if (tid < 256) {
        const float* cb = csbuf + ((N_ITER - 1) % 3) * BUFSTRIDE;  // p_acc of t=49
        float cs = 0.0f;
#pragma unroll
        for (int s = 0; s < NSHARD; s++)
            cs += __hip_atomic_load(&cb[s * 256 + tid], __ATOMIC_RELAXED,
                                    __HIP_MEMORY_SCOPE_AGENT);
        ev_lds[(tid >> 4) * EVPAD + (tid & 15)] = NUKS * __builtin_amdgcn_rcpf(cs);
    }
    __syncthreads();
    float ef[16];
#pragma unroll
    for (int j = 0; j < 16; j++) ef[j] = ev_lds[j * EVPAD + m];
    float accv = 0.0f;
#pragma unroll
    for (int rg = 0; rg < 4; rg++) {
        const int row = blk * 256 + w * 16 + q * 4 + rg;
        float a[16];
#pragma unroll
        for (int j = 0; j < 16; j++)
            a[j] = fabsf(coord[(size_t)row * 256 + j * 16 + m]);
        float mx = a[0];
#pragma unroll
        for (int j = 1; j < 16; j++) mx = fmaxf(mx, a[j]);
        mx = fmaxf(mx, __shfl_xor(mx, 8, 64));   // row spans the 16 m-lanes
        mx = fmaxf(mx, __shfl_xor(mx, 4, 64));
        mx = fmaxf(mx, __shfl_xor(mx, 2, 64));
        mx = fmaxf(mx, __shfl_xor(mx, 1, 64));
        float ex[16];
        float zs = 0.0f;
#pragma unroll
        for (int j = 0; j < 16; j++) { ex[j] = __expf(a[j] - mx); zs += ex[j]; }
        zs += __shfl_xor(zs, 8, 64);
        zs += __shfl_xor(zs, 4, 64);
        zs += __shfl_xor(zs, 2, 64);
        zs += __shfl_xor(zs, 1, 64);
        float s = 0.0f;
#pragma unroll
        for (int j = 0; j < 16; j++) {
            float Cj = -0.1f * __logf(kvf[rg][j] * INV_KSCALE - 1e-8f);
            s += kvf[rg][j] * ef[j] * Cj * ex[j];
        }
        accv = fmaf(s, ai_reg[rg] * INV_KSCALE * __builtin_amdgcn_rcpf(zs), accv);
    }
    accv = wave_sum(accv);
    if (lane == 0) wpart[w] = accv;
    __syncthreads();
    if (tid == 0) {
        float tot = 0.0f;
#pragma unroll
        for (int i = 0; i < 16; i++) tot += wpart[i];
        atomicAdd(out, tot);
    }
}

extern "C" void kernel_launch(void* const* d_in, const int* in_sizes, int n_in,
                              void* d_out, int out_size, void* d_ws, size_t ws_size,
                              hipStream_t stream) {
    const float* x = (const float*)d_in[0];
    const float* proto = (const float*)d_in[1];
    const float* coord = (const float*)d_in[2];
    float* out = (float*)d_out;
    char* ws = (char*)d_ws;
    // workspace layout (kappa retired; offsets kept stable)
    short* bh_s = (short*)(ws + 33554432);                  // 64 KB (swizzled hi plane)
    short* bl_s = bh_s + 32768;                             // 64 KB (swizzled lo plane)
    unsigned* bar = (unsigned*)(ws + 33554432 + 131072 + 262144);       // 208 KB barrier region
    float* csbuf = (float*)(ws + 33554432 + 131072 + 262144 + 262144);  // 48 KB

    hipLaunchKernelGGL(proto_norm_init, dim3(264), dim3(64), 0, stream,
                       proto, bh_s, bl_s, csbuf, bar, out);
    hipLaunchKernelGGL(sinkhorn_persist, dim3(NBLK), dim3(1024), 0, stream,
                       x, bh_s, bl_s, csbuf, coord, bar, out);
}